// Round 5
// baseline (129.908 us; speedup 1.0000x reference)
//
#include <hip/hip_runtime.h>

namespace {

constexpr int Tt = 32;    // frames (t)
constexpr int Ss = 784;   // floats per row (h*w)

// ---------------------------------------------------------------------------
// Kernel 1: per-(b,c) Gram.  part[bc][q*32+k] = sum_s x[bc][q][s]*x[bc][k][s]
// 1024 blocks x 256 threads (4 waves), 3 blocks/CU.
// Lane = (g<<4)|(ty<<2)|tx : 8x8 register tile (q-rows 8ty+i, k-rows 8tx+j),
// g in 0..3 splits float4-columns (c = 4m+g) -> 16 b128 reads per 512 FLOP/lane
// (2x better LDS-instr/FLOP than round-3's 4x4). LDS tile [32][96] float4
// (48 KB, stride 96 == 0 mod 8) with XOR swizzle c ^ ((row>>3)<<2):
// a-reads conflict-free, b-reads 2-way (free). 196 cols = 2 chunks of 96 +
// 4-col tail direct from global (wave w takes col 192+w, g==0 lanes only).
// g-partials summed by 2 __shfl_xor butterflies; waves reduced via LDS alias.
// ---------------------------------------------------------------------------
__global__ __launch_bounds__(256, 3) void gram_partial(const float* __restrict__ x,
                                                       float* __restrict__ part) {
  const int bc = blockIdx.x;                       // b*64 + c
  const float* __restrict__ xb = x + (size_t)bc * (Tt * Ss);
  const int tid  = threadIdx.x;
  const int w    = tid >> 6;          // wave 0..3
  const int lane = tid & 63;
  const int g    = lane >> 4;         // col-group 0..3
  const int ty   = (lane >> 2) & 3;   // q-block (rows 8ty..8ty+7)
  const int tx   = lane & 3;          // k-block (rows 8tx..8tx+7)

  __shared__ float4 tile[32][96];     // 48 KB; aliased as mtmp after compute

  float acc[8][8] = {};

  for (int ch = 0; ch < 2; ++ch) {
    // stage 32 rows x 96 float4 (1536 B contiguous per row), swizzled
#pragma unroll
    for (int it = 0; it < 12; ++it) {
      const int f   = tid + 256 * it;
      const int row = f / 96;
      const int c   = f - row * 96;
      tile[row][c ^ ((row >> 3) << 2)] =
          *reinterpret_cast<const float4*>(xb + row * Ss + ch * 384 + 4 * c);
    }
    __syncthreads();

    for (int m = w; m < 24; m += 4) {
      const int c = 4 * m + g;
      float4 a4[8], b4[8];
#pragma unroll
      for (int i = 0; i < 8; ++i) a4[i] = tile[8 * ty + i][c ^ (ty << 2)];
#pragma unroll
      for (int j = 0; j < 8; ++j) b4[j] = tile[8 * tx + j][c ^ (tx << 2)];
#pragma unroll
      for (int i = 0; i < 8; ++i)
#pragma unroll
        for (int j = 0; j < 8; ++j)
          acc[i][j] += a4[i].x * b4[j].x + a4[i].y * b4[j].y +
                       a4[i].z * b4[j].z + a4[i].w * b4[j].w;
    }
    __syncthreads();
  }

  // tail cols 192..195 (floats 768..783): wave w -> col 192+w, g==0 lanes only
  if (g == 0) {
    const int s0 = 768 + 4 * w;
    float4 a4[8], b4[8];
#pragma unroll
    for (int i = 0; i < 8; ++i)
      a4[i] = *reinterpret_cast<const float4*>(xb + (8 * ty + i) * Ss + s0);
#pragma unroll
    for (int j = 0; j < 8; ++j)
      b4[j] = *reinterpret_cast<const float4*>(xb + (8 * tx + j) * Ss + s0);
#pragma unroll
    for (int i = 0; i < 8; ++i)
#pragma unroll
      for (int j = 0; j < 8; ++j)
        acc[i][j] += a4[i].x * b4[j].x + a4[i].y * b4[j].y +
                     a4[i].z * b4[j].z + a4[i].w * b4[j].w;
  }

  // reduce over g (lane bits 4 and 5): butterfly — every lane ends with the sum
#pragma unroll
  for (int i = 0; i < 8; ++i)
#pragma unroll
    for (int j = 0; j < 8; ++j) {
      float v = acc[i][j];
      v += __shfl_xor(v, 16, 64);
      v += __shfl_xor(v, 32, 64);
      acc[i][j] = v;
    }

  // per-wave partials into LDS (aliases tile; all tile reads complete)
  float* mtmpf = reinterpret_cast<float*>(tile);
  if (g == 0) {
    float4* m4 = reinterpret_cast<float4*>(mtmpf) + w * 256;
#pragma unroll
    for (int i = 0; i < 8; ++i) {
      float4 v0, v1;
      v0.x = acc[i][0]; v0.y = acc[i][1]; v0.z = acc[i][2]; v0.w = acc[i][3];
      v1.x = acc[i][4]; v1.y = acc[i][5]; v1.z = acc[i][6]; v1.w = acc[i][7];
      m4[(8 * ty + i) * 8 + 2 * tx + 0] = v0;
      m4[(8 * ty + i) * 8 + 2 * tx + 1] = v1;
    }
  }
  __syncthreads();

  // sum the 4 wave-partials, vectorized
  const float4* m4r = reinterpret_cast<const float4*>(mtmpf);
  const float4 s0 = m4r[tid], s1 = m4r[256 + tid], s2 = m4r[512 + tid], s3 = m4r[768 + tid];
  float4 r;
  r.x = (s0.x + s1.x) + (s2.x + s3.x);
  r.y = (s0.y + s1.y) + (s2.y + s3.y);
  r.z = (s0.z + s1.z) + (s2.z + s3.z);
  r.w = (s0.w + s1.w) + (s2.w + s3.w);
  reinterpret_cast<float4*>(part + (size_t)bc * 1024)[tid] = r;
}

// ---------------------------------------------------------------------------
// Kernel 2: reduce partials over c.  msum[b][e] = sum_c part[b*64+c][e]
// ---------------------------------------------------------------------------
__global__ __launch_bounds__(256) void reduce_c(const float* __restrict__ part,
                                                float* __restrict__ msum) {
  const int bid = blockIdx.x;                // 0..63
  const int b   = bid >> 2;
  const int e   = (bid & 3) * 256 + threadIdx.x;   // 0..1023
  const float* __restrict__ p = part + (size_t)b * 64 * 1024 + e;
  float s0 = 0.f, s1 = 0.f, s2 = 0.f, s3 = 0.f;
#pragma unroll
  for (int c = 0; c < 64; c += 4) {
    s0 += p[(size_t)(c + 0) * 1024];
    s1 += p[(size_t)(c + 1) * 1024];
    s2 += p[(size_t)(c + 2) * 1024];
    s3 += p[(size_t)(c + 3) * 1024];
  }
  msum[b * 1024 + e] = (s0 + s1) + (s2 + s3);
}

// ---------------------------------------------------------------------------
// Kernel 3: softmax over the BATCH axis + transpose to [k][q]-major.
// ---------------------------------------------------------------------------
__global__ __launch_bounds__(256) void softmax_b(const float* __restrict__ msum,
                                                 float* __restrict__ mt) {
  const int e = blockIdx.x * 256 + threadIdx.x;    // q*32 + k
  float l[16];
  float mx = -3.4e38f;
#pragma unroll
  for (int b = 0; b < 16; ++b) {
    l[b] = msum[b * 1024 + e];
    mx = fmaxf(mx, l[b]);
  }
  float s = 0.f;
#pragma unroll
  for (int b = 0; b < 16; ++b) {
    l[b] = expf(l[b] - mx);
    s += l[b];
  }
  const float inv = 1.f / s;
  const int et = (e & 31) * 32 + (e >> 5);         // k*32 + q
#pragma unroll
  for (int b = 0; b < 16; ++b) mt[b * 1024 + et] = l[b] * inv;
}

// ---------------------------------------------------------------------------
// Kernel 4: PV.  out[bc][q][s] = sum_k mt[b][k*32+q] * xv[bc][k][s]
// 4096 blocks = bc*4 + s-chunk; 256 threads = 4 waves (q-groups of 8).
// NO LDS: m-coefficients are wave-uniform -> readfirstlane'd base + direct
// global reads (scalar pipe, L2-hot 64 KB). xv streamed with explicit 4-deep
// double-buffered float4 staging (va/vb) -> ~3 KB in flight per wave.
// ---------------------------------------------------------------------------
__global__ __launch_bounds__(256) void pv(const float* __restrict__ xv,
                                          const float* __restrict__ mt,
                                          float* __restrict__ out) {
  const int gbl   = blockIdx.x;               // bc*4 + chunk
  const int bc    = gbl >> 2;
  const int chunk = gbl & 3;
  const int b     = bc >> 6;
  const float* __restrict__ xvb = xv + (size_t)bc * (Tt * Ss) + chunk * 196;
  float* __restrict__ ob        = out + (size_t)bc * (Tt * Ss) + chunk * 196;

  const int tid  = threadIdx.x;
  const int w    = tid >> 6;
  const int lane = tid & 63;
  const int q0   = __builtin_amdgcn_readfirstlane(8 * w);
  const int moff = __builtin_amdgcn_readfirstlane(b * 1024 + q0);
  const float* __restrict__ mrow = mt + moff;     // mrow[k*32 + r], uniform

  if (lane < 49) {
    const float* __restrict__ src = xvb + 4 * lane;
    float4 acc[8] = {};
    float4 va[4], vb4[4];
#pragma unroll
    for (int t = 0; t < 4; ++t)
      va[t] = *reinterpret_cast<const float4*>(src + (size_t)t * Ss);

#pragma unroll
    for (int kc = 0; kc < 4; ++kc) {
      // prefetch next 4 k-rows (k = 8kc+4 .. 8kc+7; always in range)
#pragma unroll
      for (int t = 0; t < 4; ++t)
        vb4[t] = *reinterpret_cast<const float4*>(src + (size_t)(8 * kc + 4 + t) * Ss);
      // consume va (k = 8kc .. 8kc+3)
#pragma unroll
      for (int t = 0; t < 4; ++t) {
        const int k = 8 * kc + t;
#pragma unroll
        for (int r = 0; r < 8; ++r) {
          const float m = mrow[k * 32 + r];
          acc[r].x += m * va[t].x; acc[r].y += m * va[t].y;
          acc[r].z += m * va[t].z; acc[r].w += m * va[t].w;
        }
      }
      // prefetch following 4 k-rows into va
      if (kc < 3) {
#pragma unroll
        for (int t = 0; t < 4; ++t)
          va[t] = *reinterpret_cast<const float4*>(src + (size_t)(8 * kc + 8 + t) * Ss);
      }
      // consume vb4 (k = 8kc+4 .. 8kc+7)
#pragma unroll
      for (int t = 0; t < 4; ++t) {
        const int k = 8 * kc + 4 + t;
#pragma unroll
        for (int r = 0; r < 8; ++r) {
          const float m = mrow[k * 32 + r];
          acc[r].x += m * vb4[t].x; acc[r].y += m * vb4[t].y;
          acc[r].z += m * vb4[t].z; acc[r].w += m * vb4[t].w;
        }
      }
    }

#pragma unroll
    for (int r = 0; r < 8; ++r)
      *reinterpret_cast<float4*>(ob + (size_t)(q0 + r) * Ss + 4 * lane) = acc[r];
  }
}

}  // namespace

extern "C" void kernel_launch(void* const* d_in, const int* in_sizes, int n_in,
                              void* d_out, int out_size, void* d_ws, size_t ws_size,
                              hipStream_t stream) {
  const float* x  = (const float*)d_in[0];
  const float* xv = (const float*)d_in[1];
  float* out = (float*)d_out;

  // workspace (fp32), ~4.2 MiB total:
  float* part = (float*)d_ws;            // 1024 x 1024
  float* msum = part + 1024 * 1024;      // 16 x 1024
  float* mt   = msum + 16 * 1024;        // 16 x 1024 (k-major softmax weights)

  gram_partial<<<dim3(1024), dim3(256), 0, stream>>>(x, part);
  reduce_c<<<dim3(64), dim3(256), 0, stream>>>(part, msum);
  softmax_b<<<dim3(4), dim3(256), 0, stream>>>(msum, mt);
  pv<<<dim3(4096), dim3(256), 0, stream>>>(xv, mt, out);
}

// Round 6
// 122.936 us; speedup vs baseline: 1.0567x; 1.0567x over previous
//
#include <hip/hip_runtime.h>

namespace {

constexpr int Tt = 32;    // frames (t)
constexpr int Ss = 784;   // floats per row (h*w)

// ---------------------------------------------------------------------------
// Kernel 1: per-(b,c) Gram.  part[bc][q*32+k] = sum_s x[bc][q][s]*x[bc][k][s]
// 1024 blocks x 256 threads (4 waves), LDS 48 KB -> 3 blocks/CU (3 waves/SIMD,
// VGPR cap 170). Lane = (g<<4)|(ty<<2)|tx : 8x8 register tile, g in 0..3
// splits float4-columns (c = 4m+g) -> 16 b128 reads per 256 FMA-instr.
// LDS tile [32][96] float4, XOR swizzle c ^ ((row>>3)<<2): a/b reads 2-way
// max (free), staging conflict-free (verified round 5: 131K conflicts only).
// THIS ROUND'S CHANGE vs r5: b-reads explicitly software-pipelined 2-deep
// with rotating statically-renamed regs + explicit 4-FMA chains, so live regs
// ~120 (not 128+) and the compiler keeps reads in flight instead of
// serializing (r5: VGPR=84 -> 1-deep reads -> stall-bound 94 us).
// ---------------------------------------------------------------------------
__global__ __launch_bounds__(256, 3) void gram_partial(const float* __restrict__ x,
                                                       float* __restrict__ part) {
  const int bc = blockIdx.x;                       // b*64 + c
  const float* __restrict__ xb = x + (size_t)bc * (Tt * Ss);
  const int tid  = threadIdx.x;
  const int w    = tid >> 6;          // wave 0..3
  const int lane = tid & 63;
  const int g    = lane >> 4;         // col-group 0..3
  const int ty   = (lane >> 2) & 3;   // q-block (rows 8ty..8ty+7)
  const int tx   = lane & 3;          // k-block (rows 8tx..8tx+7)

  __shared__ float4 tile[32][96];     // 48 KB; aliased as mtmp after compute

  float acc[8][8] = {};

  for (int ch = 0; ch < 2; ++ch) {
    // stage 32 rows x 96 float4 (1536 B contiguous per row), swizzled
#pragma unroll
    for (int it = 0; it < 12; ++it) {
      const int f   = tid + 256 * it;
      const int row = f / 96;
      const int c   = f - row * 96;
      tile[row][c ^ ((row >> 3) << 2)] =
          *reinterpret_cast<const float4*>(xb + row * Ss + ch * 384 + 4 * c);
    }
    __syncthreads();

    for (int m = w; m < 24; m += 4) {
      const int ca = (4 * m + g) ^ (ty << 2);
      const int cb = (4 * m + g) ^ (tx << 2);
      // issue all 8 a-reads (independent, stay in flight)
      float4 a4[8];
#pragma unroll
      for (int i = 0; i < 8; ++i) a4[i] = tile[8 * ty + i][ca];
      // b-reads: 2-deep rotating pipeline, statically renamed via unroll
      float4 bcur = tile[8 * tx + 0][cb];
      float4 bnxt = tile[8 * tx + 1][cb];
#pragma unroll
      for (int j = 0; j < 8; ++j) {
        const float4 bj = bcur;
        bcur = bnxt;
        if (j < 6) bnxt = tile[8 * tx + j + 2][cb];
#pragma unroll
        for (int i = 0; i < 8; ++i) {
          acc[i][j] = __builtin_fmaf(a4[i].x, bj.x,
                      __builtin_fmaf(a4[i].y, bj.y,
                      __builtin_fmaf(a4[i].z, bj.z,
                      __builtin_fmaf(a4[i].w, bj.w, acc[i][j]))));
        }
      }
    }
    __syncthreads();
  }

  // tail cols 192..195 (floats 768..783): wave w -> col 192+w, g==0 lanes only
  if (g == 0) {
    const int s0 = 768 + 4 * w;
    float4 a4[8], b4[8];
#pragma unroll
    for (int i = 0; i < 8; ++i)
      a4[i] = *reinterpret_cast<const float4*>(xb + (8 * ty + i) * Ss + s0);
#pragma unroll
    for (int j = 0; j < 8; ++j)
      b4[j] = *reinterpret_cast<const float4*>(xb + (8 * tx + j) * Ss + s0);
#pragma unroll
    for (int i = 0; i < 8; ++i)
#pragma unroll
      for (int j = 0; j < 8; ++j) {
        acc[i][j] = __builtin_fmaf(a4[i].x, b4[j].x,
                    __builtin_fmaf(a4[i].y, b4[j].y,
                    __builtin_fmaf(a4[i].z, b4[j].z,
                    __builtin_fmaf(a4[i].w, b4[j].w, acc[i][j]))));
      }
  }

  // reduce over g (lane bits 4 and 5): butterfly — every lane ends with the sum
#pragma unroll
  for (int i = 0; i < 8; ++i)
#pragma unroll
    for (int j = 0; j < 8; ++j) {
      float v = acc[i][j];
      v += __shfl_xor(v, 16, 64);
      v += __shfl_xor(v, 32, 64);
      acc[i][j] = v;
    }

  // per-wave partials into LDS (aliases tile; all tile reads complete)
  __syncthreads();
  float* mtmpf = reinterpret_cast<float*>(tile);
  if (g == 0) {
    float4* m4 = reinterpret_cast<float4*>(mtmpf) + w * 256;
#pragma unroll
    for (int i = 0; i < 8; ++i) {
      float4 v0, v1;
      v0.x = acc[i][0]; v0.y = acc[i][1]; v0.z = acc[i][2]; v0.w = acc[i][3];
      v1.x = acc[i][4]; v1.y = acc[i][5]; v1.z = acc[i][6]; v1.w = acc[i][7];
      m4[(8 * ty + i) * 8 + 2 * tx + 0] = v0;
      m4[(8 * ty + i) * 8 + 2 * tx + 1] = v1;
    }
  }
  __syncthreads();

  // sum the 4 wave-partials, vectorized
  const float4* m4r = reinterpret_cast<const float4*>(mtmpf);
  const float4 s0 = m4r[tid], s1 = m4r[256 + tid], s2 = m4r[512 + tid], s3 = m4r[768 + tid];
  float4 r;
  r.x = (s0.x + s1.x) + (s2.x + s3.x);
  r.y = (s0.y + s1.y) + (s2.y + s3.y);
  r.z = (s0.z + s1.z) + (s2.z + s3.z);
  r.w = (s0.w + s1.w) + (s2.w + s3.w);
  reinterpret_cast<float4*>(part + (size_t)bc * 1024)[tid] = r;
}

// ---------------------------------------------------------------------------
// Kernel 2: reduce partials over c.  msum[b][e] = sum_c part[b*64+c][e]
// ---------------------------------------------------------------------------
__global__ __launch_bounds__(256) void reduce_c(const float* __restrict__ part,
                                                float* __restrict__ msum) {
  const int bid = blockIdx.x;                // 0..63
  const int b   = bid >> 2;
  const int e   = (bid & 3) * 256 + threadIdx.x;   // 0..1023
  const float* __restrict__ p = part + (size_t)b * 64 * 1024 + e;
  float s0 = 0.f, s1 = 0.f, s2 = 0.f, s3 = 0.f;
#pragma unroll
  for (int c = 0; c < 64; c += 4) {
    s0 += p[(size_t)(c + 0) * 1024];
    s1 += p[(size_t)(c + 1) * 1024];
    s2 += p[(size_t)(c + 2) * 1024];
    s3 += p[(size_t)(c + 3) * 1024];
  }
  msum[b * 1024 + e] = (s0 + s1) + (s2 + s3);
}

// ---------------------------------------------------------------------------
// Kernel 3: softmax over the BATCH axis + transpose to [k][q]-major.
// ---------------------------------------------------------------------------
__global__ __launch_bounds__(256) void softmax_b(const float* __restrict__ msum,
                                                 float* __restrict__ mt) {
  const int e = blockIdx.x * 256 + threadIdx.x;    // q*32 + k
  float l[16];
  float mx = -3.4e38f;
#pragma unroll
  for (int b = 0; b < 16; ++b) {
    l[b] = msum[b * 1024 + e];
    mx = fmaxf(mx, l[b]);
  }
  float s = 0.f;
#pragma unroll
  for (int b = 0; b < 16; ++b) {
    l[b] = expf(l[b] - mx);
    s += l[b];
  }
  const float inv = 1.f / s;
  const int et = (e & 31) * 32 + (e >> 5);         // k*32 + q
#pragma unroll
  for (int b = 0; b < 16; ++b) mt[b * 1024 + et] = l[b] * inv;
}

// ---------------------------------------------------------------------------
// Kernel 4: PV.  out[bc][q][s] = sum_k mt[b][k*32+q] * xv[bc][k][s]
// (unchanged from round 4/5 — measured at its ~32 us HBM floor)
// ---------------------------------------------------------------------------
__global__ __launch_bounds__(256) void pv(const float* __restrict__ xv,
                                          const float* __restrict__ mt,
                                          float* __restrict__ out) {
  const int gbl   = blockIdx.x;               // bc*4 + chunk
  const int bc    = gbl >> 2;
  const int chunk = gbl & 3;
  const int b     = bc >> 6;
  const float* __restrict__ xvb = xv + (size_t)bc * (Tt * Ss) + chunk * 196;
  float* __restrict__ ob        = out + (size_t)bc * (Tt * Ss) + chunk * 196;

  const int tid  = threadIdx.x;
  const int w    = tid >> 6;
  const int lane = tid & 63;
  const int q0   = __builtin_amdgcn_readfirstlane(8 * w);
  const int moff = __builtin_amdgcn_readfirstlane(b * 1024 + q0);
  const float* __restrict__ mrow = mt + moff;     // mrow[k*32 + r], uniform

  if (lane < 49) {
    const float* __restrict__ src = xvb + 4 * lane;
    float4 acc[8] = {};
    float4 va[4], vb4[4];
#pragma unroll
    for (int t = 0; t < 4; ++t)
      va[t] = *reinterpret_cast<const float4*>(src + (size_t)t * Ss);

#pragma unroll
    for (int kc = 0; kc < 4; ++kc) {
#pragma unroll
      for (int t = 0; t < 4; ++t)
        vb4[t] = *reinterpret_cast<const float4*>(src + (size_t)(8 * kc + 4 + t) * Ss);
#pragma unroll
      for (int t = 0; t < 4; ++t) {
        const int k = 8 * kc + t;
#pragma unroll
        for (int r = 0; r < 8; ++r) {
          const float m = mrow[k * 32 + r];
          acc[r].x += m * va[t].x; acc[r].y += m * va[t].y;
          acc[r].z += m * va[t].z; acc[r].w += m * va[t].w;
        }
      }
      if (kc < 3) {
#pragma unroll
        for (int t = 0; t < 4; ++t)
          va[t] = *reinterpret_cast<const float4*>(src + (size_t)(8 * kc + 8 + t) * Ss);
      }
#pragma unroll
      for (int t = 0; t < 4; ++t) {
        const int k = 8 * kc + 4 + t;
#pragma unroll
        for (int r = 0; r < 8; ++r) {
          const float m = mrow[k * 32 + r];
          acc[r].x += m * vb4[t].x; acc[r].y += m * vb4[t].y;
          acc[r].z += m * vb4[t].z; acc[r].w += m * vb4[t].w;
        }
      }
    }

#pragma unroll
    for (int r = 0; r < 8; ++r)
      *reinterpret_cast<float4*>(ob + (size_t)(q0 + r) * Ss + 4 * lane) = acc[r];
  }
}

}  // namespace

extern "C" void kernel_launch(void* const* d_in, const int* in_sizes, int n_in,
                              void* d_out, int out_size, void* d_ws, size_t ws_size,
                              hipStream_t stream) {
  const float* x  = (const float*)d_in[0];
  const float* xv = (const float*)d_in[1];
  float* out = (float*)d_out;

  // workspace (fp32), ~4.2 MiB total:
  float* part = (float*)d_ws;            // 1024 x 1024
  float* msum = part + 1024 * 1024;      // 16 x 1024
  float* mt   = msum + 16 * 1024;        // 16 x 1024 (k-major softmax weights)

  gram_partial<<<dim3(1024), dim3(256), 0, stream>>>(x, part);
  reduce_c<<<dim3(64), dim3(256), 0, stream>>>(part, msum);
  softmax_b<<<dim3(4), dim3(256), 0, stream>>>(msum, mt);
  pv<<<dim3(4096), dim3(256), 0, stream>>>(xv, mt, out);
}

// Round 7
// 87.870 us; speedup vs baseline: 1.4784x; 1.3991x over previous
//
#include <hip/hip_runtime.h>

namespace {

constexpr int Tt = 32;    // frames (t)
constexpr int Ss = 784;   // floats per row (h*w)

using bf16x8 = __attribute__((ext_vector_type(8))) short;
using f32x4  = __attribute__((ext_vector_type(4))) float;

// split fp32 -> hi (truncated bf16) + lo (bf16 of residual); pack 2 per uint
__device__ inline void cvt2(float a, float b, unsigned& h, unsigned& l) {
  const unsigned ha = __float_as_uint(a) >> 16;
  const unsigned hb = __float_as_uint(b) >> 16;
  const float ra = a - __uint_as_float(ha << 16);
  const float rb = b - __uint_as_float(hb << 16);
  const unsigned la = __float_as_uint(ra) >> 16;
  const unsigned lb = __float_as_uint(rb) >> 16;
  h = ha | (hb << 16);
  l = la | (lb << 16);
}

// ---------------------------------------------------------------------------
// Kernel 1: per-(b,c) Gram via split-bf16 MFMA.
//   part[bc][q*32+k] = sum_s x[bc][q][s]*x[bc][k][s]
// 1024 blocks x 256 threads (4 waves), LDS 52 KB -> 3 blocks/CU.
// x = hi + lo (bf16 pair). C = HI*HI^T + HI*LO^T + LO*HI^T (lo*lo dropped,
// ~2^-17 relative — logit error ~0.002, negligible vs fp32-path margin).
// Two phases: stage 13 (then 12) K-steps of 32 into fragment-ordered LDS
// (chunk = 16B = 8 bf16 of one (row,kgroup); idx = kgroup*32+row -> frag read
// is 256 B contiguous per 16 lanes, conflict-free). s in [784,800) zero-padded.
// Each wave owns K-steps ks % 4 == w; 12 MFMA per K-step; cross-wave reduce
// + D1+D2+D3 combine in LDS epilogue (padded stride 33).
// ---------------------------------------------------------------------------
__global__ __launch_bounds__(256, 3) void gram_partial(const float* __restrict__ x,
                                                       float* __restrict__ part) {
  const int bc = blockIdx.x;                       // b*64 + c
  const float* __restrict__ xb = x + (size_t)bc * (Tt * Ss);
  const int tid  = threadIdx.x;
  const int w    = tid >> 6;          // wave 0..3
  const int lane = tid & 63;

  __shared__ uint4 HI[13 * 128];      // 26624 B
  __shared__ uint4 LO[13 * 128];      // 26624 B

  f32x4 d1[2][2], d2[2][2], d3[2][2];
#pragma unroll
  for (int i = 0; i < 2; ++i)
#pragma unroll
    for (int j = 0; j < 2; ++j) { d1[i][j] = 0.f; d2[i][j] = 0.f; d3[i][j] = 0.f; }

  const int fbase = ((lane >> 4) << 5) + (lane & 15);   // frag chunk idx within kstep

#pragma unroll
  for (int phase = 0; phase < 2; ++phase) {
    const int sb  = phase ? 416 : 0;
    const int nks = phase ? 12 : 13;

    // ---- stage: fp32 -> hi/lo bf16, fragment-ordered chunks of 8 ----
    for (int f = tid; f < nks * 128; f += 256) {
      const int ks  = f >> 7;
      const int idx = f & 127;
      const int kg  = idx >> 5;
      const int row = idx & 31;
      const int s   = sb + ks * 32 + kg * 8;
      uint4 h = {0u, 0u, 0u, 0u}, l = {0u, 0u, 0u, 0u};
      if (s < 784) {
        const float* p = xb + row * Ss + s;
        const float4 v0 = *reinterpret_cast<const float4*>(p);
        const float4 v1 = *reinterpret_cast<const float4*>(p + 4);
        cvt2(v0.x, v0.y, h.x, l.x);
        cvt2(v0.z, v0.w, h.y, l.y);
        cvt2(v1.x, v1.y, h.z, l.z);
        cvt2(v1.z, v1.w, h.w, l.w);
      }
      HI[f] = h;
      LO[f] = l;
    }
    __syncthreads();

    // ---- MFMA: wave w owns ksteps ks % 4 == w ----
    for (int ks = w; ks < nks; ks += 4) {
      const int base = ks * 128 + fbase;
      const uint4 h0u = HI[base], h1u = HI[base + 16];
      const uint4 l0u = LO[base], l1u = LO[base + 16];
      const bf16x8 h0 = __builtin_bit_cast(bf16x8, h0u);
      const bf16x8 h1 = __builtin_bit_cast(bf16x8, h1u);
      const bf16x8 l0 = __builtin_bit_cast(bf16x8, l0u);
      const bf16x8 l1 = __builtin_bit_cast(bf16x8, l1u);
      d1[0][0] = __builtin_amdgcn_mfma_f32_16x16x32_bf16(h0, h0, d1[0][0], 0, 0, 0);
      d1[0][1] = __builtin_amdgcn_mfma_f32_16x16x32_bf16(h0, h1, d1[0][1], 0, 0, 0);
      d1[1][0] = __builtin_amdgcn_mfma_f32_16x16x32_bf16(h1, h0, d1[1][0], 0, 0, 0);
      d1[1][1] = __builtin_amdgcn_mfma_f32_16x16x32_bf16(h1, h1, d1[1][1], 0, 0, 0);
      d2[0][0] = __builtin_amdgcn_mfma_f32_16x16x32_bf16(h0, l0, d2[0][0], 0, 0, 0);
      d2[0][1] = __builtin_amdgcn_mfma_f32_16x16x32_bf16(h0, l1, d2[0][1], 0, 0, 0);
      d2[1][0] = __builtin_amdgcn_mfma_f32_16x16x32_bf16(h1, l0, d2[1][0], 0, 0, 0);
      d2[1][1] = __builtin_amdgcn_mfma_f32_16x16x32_bf16(h1, l1, d2[1][1], 0, 0, 0);
      d3[0][0] = __builtin_amdgcn_mfma_f32_16x16x32_bf16(l0, h0, d3[0][0], 0, 0, 0);
      d3[0][1] = __builtin_amdgcn_mfma_f32_16x16x32_bf16(l0, h1, d3[0][1], 0, 0, 0);
      d3[1][0] = __builtin_amdgcn_mfma_f32_16x16x32_bf16(l1, h0, d3[1][0], 0, 0, 0);
      d3[1][1] = __builtin_amdgcn_mfma_f32_16x16x32_bf16(l1, h1, d3[1][1], 0, 0, 0);
    }
    __syncthreads();   // all frag reads done before restage / epilogue alias
  }

  // ---- epilogue: combine D1+D2+D3, reduce over 4 waves ----
  float* mtmp = reinterpret_cast<float*>(HI);   // [4][32*33] = 16896 B, aliases HI
#pragma unroll
  for (int i = 0; i < 2; ++i)
#pragma unroll
    for (int j = 0; j < 2; ++j) {
      const f32x4 s4 = d1[i][j] + d2[i][j] + d3[i][j];
#pragma unroll
      for (int r = 0; r < 4; ++r) {
        const int row = i * 16 + ((lane >> 4) << 2) + r;   // m89-verified C/D map
        const int col = j * 16 + (lane & 15);
        mtmp[w * 1056 + row * 33 + col] = s4[r];
      }
    }
  __syncthreads();

  const int e0 = tid * 4;
  float tmp[4];
#pragma unroll
  for (int u = 0; u < 4; ++u) {
    const int row = (e0 + u) >> 5;
    const int col = (e0 + u) & 31;
    float ss = 0.f;
#pragma unroll
    for (int ww = 0; ww < 4; ++ww) ss += mtmp[ww * 1056 + row * 33 + col];
    tmp[u] = ss;
  }
  float4 o4;
  o4.x = tmp[0]; o4.y = tmp[1]; o4.z = tmp[2]; o4.w = tmp[3];
  *reinterpret_cast<float4*>(part + (size_t)bc * 1024 + e0) = o4;
}

// ---------------------------------------------------------------------------
// Kernel 2: reduce partials over c.  msum[b][e] = sum_c part[b*64+c][e]
// ---------------------------------------------------------------------------
__global__ __launch_bounds__(256) void reduce_c(const float* __restrict__ part,
                                                float* __restrict__ msum) {
  const int bid = blockIdx.x;                // 0..63
  const int b   = bid >> 2;
  const int e   = (bid & 3) * 256 + threadIdx.x;   // 0..1023
  const float* __restrict__ p = part + (size_t)b * 64 * 1024 + e;
  float s0 = 0.f, s1 = 0.f, s2 = 0.f, s3 = 0.f;
#pragma unroll
  for (int c = 0; c < 64; c += 4) {
    s0 += p[(size_t)(c + 0) * 1024];
    s1 += p[(size_t)(c + 1) * 1024];
    s2 += p[(size_t)(c + 2) * 1024];
    s3 += p[(size_t)(c + 3) * 1024];
  }
  msum[b * 1024 + e] = (s0 + s1) + (s2 + s3);
}

// ---------------------------------------------------------------------------
// Kernel 3: softmax over the BATCH axis + transpose to [k][q]-major.
// ---------------------------------------------------------------------------
__global__ __launch_bounds__(256) void softmax_b(const float* __restrict__ msum,
                                                 float* __restrict__ mt) {
  const int e = blockIdx.x * 256 + threadIdx.x;    // q*32 + k
  float l[16];
  float mx = -3.4e38f;
#pragma unroll
  for (int b = 0; b < 16; ++b) {
    l[b] = msum[b * 1024 + e];
    mx = fmaxf(mx, l[b]);
  }
  float s = 0.f;
#pragma unroll
  for (int b = 0; b < 16; ++b) {
    l[b] = expf(l[b] - mx);
    s += l[b];
  }
  const float inv = 1.f / s;
  const int et = (e & 31) * 32 + (e >> 5);         // k*32 + q
#pragma unroll
  for (int b = 0; b < 16; ++b) mt[b * 1024 + et] = l[b] * inv;
}

// ---------------------------------------------------------------------------
// Kernel 4: PV.  out[bc][q][s] = sum_k mt[b][k*32+q] * xv[bc][k][s]
// (unchanged from round 4/5 — measured at its ~31-32 us HBM floor)
// ---------------------------------------------------------------------------
__global__ __launch_bounds__(256) void pv(const float* __restrict__ xv,
                                          const float* __restrict__ mt,
                                          float* __restrict__ out) {
  const int gbl   = blockIdx.x;               // bc*4 + chunk
  const int bc    = gbl >> 2;
  const int chunk = gbl & 3;
  const int b     = bc >> 6;
  const float* __restrict__ xvb = xv + (size_t)bc * (Tt * Ss) + chunk * 196;
  float* __restrict__ ob        = out + (size_t)bc * (Tt * Ss) + chunk * 196;

  const int tid  = threadIdx.x;
  const int w    = tid >> 6;
  const int lane = tid & 63;
  const int q0   = __builtin_amdgcn_readfirstlane(8 * w);
  const int moff = __builtin_amdgcn_readfirstlane(b * 1024 + q0);
  const float* __restrict__ mrow = mt + moff;     // mrow[k*32 + r], uniform

  if (lane < 49) {
    const float* __restrict__ src = xvb + 4 * lane;
    float4 acc[8] = {};
    float4 va[4], vb4[4];
#pragma unroll
    for (int t = 0; t < 4; ++t)
      va[t] = *reinterpret_cast<const float4*>(src + (size_t)t * Ss);

#pragma unroll
    for (int kc = 0; kc < 4; ++kc) {
#pragma unroll
      for (int t = 0; t < 4; ++t)
        vb4[t] = *reinterpret_cast<const float4*>(src + (size_t)(8 * kc + 4 + t) * Ss);
#pragma unroll
      for (int t = 0; t < 4; ++t) {
        const int k = 8 * kc + t;
#pragma unroll
        for (int r = 0; r < 8; ++r) {
          const float m = mrow[k * 32 + r];
          acc[r].x += m * va[t].x; acc[r].y += m * va[t].y;
          acc[r].z += m * va[t].z; acc[r].w += m * va[t].w;
        }
      }
      if (kc < 3) {
#pragma unroll
        for (int t = 0; t < 4; ++t)
          va[t] = *reinterpret_cast<const float4*>(src + (size_t)(8 * kc + 8 + t) * Ss);
      }
#pragma unroll
      for (int t = 0; t < 4; ++t) {
        const int k = 8 * kc + 4 + t;
#pragma unroll
        for (int r = 0; r < 8; ++r) {
          const float m = mrow[k * 32 + r];
          acc[r].x += m * vb4[t].x; acc[r].y += m * vb4[t].y;
          acc[r].z += m * vb4[t].z; acc[r].w += m * vb4[t].w;
        }
      }
    }

#pragma unroll
    for (int r = 0; r < 8; ++r)
      *reinterpret_cast<float4*>(ob + (size_t)(q0 + r) * Ss + 4 * lane) = acc[r];
  }
}

}  // namespace

extern "C" void kernel_launch(void* const* d_in, const int* in_sizes, int n_in,
                              void* d_out, int out_size, void* d_ws, size_t ws_size,
                              hipStream_t stream) {
  const float* x  = (const float*)d_in[0];
  const float* xv = (const float*)d_in[1];
  float* out = (float*)d_out;

  // workspace (fp32), ~4.2 MiB total:
  float* part = (float*)d_ws;            // 1024 x 1024
  float* msum = part + 1024 * 1024;      // 16 x 1024
  float* mt   = msum + 16 * 1024;        // 16 x 1024 (k-major softmax weights)

  gram_partial<<<dim3(1024), dim3(256), 0, stream>>>(x, part);
  reduce_c<<<dim3(64), dim3(256), 0, stream>>>(part, msum);
  softmax_b<<<dim3(4), dim3(256), 0, stream>>>(msum, mt);
  pv<<<dim3(4096), dim3(256), 0, stream>>>(xv, mt, out);
}